// Round 1
// baseline (116.303 us; speedup 1.0000x reference)
//
#include <hip/hip_runtime.h>
#include <hip/hip_bf16.h>
#include <stdint.h>

// BatchHardTripletLoss: N=4096, D=512, C=128, margin=0.3
// dist monotone-decreasing in gram => hardest-pos = min gram (same label, j!=i),
// hardest-neg = max gram (diff label). Gram symmetric => upper-triangular tiles.
//
// R1 change: tl_gram no longer stages A/B through LDS. With K=512 the old loop
// ran 16 tiny K-steps each separated by a full vmcnt(0)+lgkmcnt(0) barrier
// drain (sync-bound, ~120 TF effective). Ebf is 4 MB = L2-resident, and the
// MFMA fragment access (row=..+l16, k=quad*8) makes each row's 4 quads one
// fully-used 64B cache line (16 perfect 64B requests / wave instr). So we load
// fragments directly from global (L2) with a 2-slot register ping-pong and NO
// barriers in the main loop. Epilogue identical to the verified kernel.

#define NROW 4096
#define DIM  512
#define MARGIN 0.3f
#define BT 128
#define NTILE (NROW / BT)                 // 32
#define NPAIR (NTILE * (NTILE + 1) / 2)   // 528
#define POS_INIT 0xFFFFFFFFu
#define NEG_INIT 0u

typedef __attribute__((ext_vector_type(8))) __bf16 bf16x8;
typedef __attribute__((ext_vector_type(4))) float  f32x4;
typedef __attribute__((ext_vector_type(8))) unsigned short u16x8;

// monotone float<->uint: order-preserving for atomicMin/Max on unsigned.
// enc(finite f) can never equal POS_INIT (needs NaN) nor NEG_INIT (needs -NaN),
// so the init sentinels double as "no positive/negative seen" flags.
__device__ __forceinline__ unsigned enc(float f) {
    unsigned u = __float_as_uint(f);
    return (u & 0x80000000u) ? ~u : (u | 0x80000000u);
}
__device__ __forceinline__ float dec(unsigned e) {
    return (e & 0x80000000u) ? __uint_as_float(e & 0x7fffffffu)
                             : __uint_as_float(~e);
}

__device__ __forceinline__ unsigned short f2bf(float f) {
    __hip_bfloat16 h = __float2bfloat16(f);
    return *reinterpret_cast<unsigned short*>(&h);
}

// ---- kernel 1: L2-normalize rows -> bf16, + init reduction arrays ----
// one wave per row; 4 waves/block; 1024 blocks (first 16 also init pos/neg)
__global__ void tl_norm(const float* __restrict__ E,
                        __hip_bfloat16* __restrict__ Ebf,
                        unsigned* __restrict__ posArr,
                        unsigned* __restrict__ negArr) {
    if (blockIdx.x < 16) {
        int t = blockIdx.x * 256 + threadIdx.x;   // covers 4096
        posArr[t] = POS_INIT;
        negArr[t] = NEG_INIT;
    }
    int wave = threadIdx.x >> 6;
    int lane = threadIdx.x & 63;
    int row  = blockIdx.x * 4 + wave;

    // lane l owns 8 consecutive floats (bytes 32l..32l+31): coalesced read,
    // and one contiguous 16B bf16 store.
    const float4* src = (const float4*)(E + (size_t)row * DIM);
    float4 v0 = src[2 * lane];
    float4 v1 = src[2 * lane + 1];
    float ss = v0.x*v0.x + v0.y*v0.y + v0.z*v0.z + v0.w*v0.w
             + v1.x*v1.x + v1.y*v1.y + v1.z*v1.z + v1.w*v1.w;
    #pragma unroll
    for (int m = 32; m >= 1; m >>= 1) ss += __shfl_xor(ss, m);
    float inv = 1.0f / fmaxf(sqrtf(ss), 1e-12f);

    u16x8 o;
    o[0] = f2bf(v0.x * inv); o[1] = f2bf(v0.y * inv);
    o[2] = f2bf(v0.z * inv); o[3] = f2bf(v0.w * inv);
    o[4] = f2bf(v1.x * inv); o[5] = f2bf(v1.y * inv);
    o[6] = f2bf(v1.z * inv); o[7] = f2bf(v1.w * inv);
    ((u16x8*)(Ebf + (size_t)row * DIM))[lane] = o;
}

// ---- kernel 2: upper-triangular bf16 MFMA Gram, fragments direct from L2 ----
// 128x128 tile per block, 4 waves in 2x2, each wave 4x4 of 16x16x32 MFMA.
// No LDS staging, no barriers in the K-loop: register ping-pong prefetch.
__global__ void tl_gram(const __hip_bfloat16* __restrict__ Ebf,
                        const int* __restrict__ labels,
                        unsigned* __restrict__ posArr,
                        unsigned* __restrict__ negArr) {
    __shared__ int rowLab[BT];
    __shared__ int colLab[BT];

    // triangular decode: blockIdx.x -> (bi, bj) with bi <= bj
    int t = blockIdx.x, bi = 0, rowlen = NTILE;
    while (t >= rowlen) { t -= rowlen; rowlen--; bi++; }
    const int bj = bi + t;

    const int tid  = threadIdx.x;
    const int wave = tid >> 6;
    const int lane = tid & 63;
    const int quad = lane >> 4;
    const int l16  = lane & 15;
    const int wr   = wave >> 1;   // wave row (0..1): rows wr*64..+63
    const int wc   = wave & 1;    // wave col (0..1): cols wc*64..+63
    const int tileI = bi * BT;
    const int tileJ = bj * BT;
    const bool diag = (bi == bj);

    if (tid < BT) rowLab[tid] = labels[tileI + tid];
    else          colLab[tid - BT] = labels[tileJ + (tid - BT)];
    __syncthreads();   // the only block-wide sync

    // fragment source: row = base + frag*16 + l16, k = k0 + quad*8.
    // 4 quads of one row span 64 contiguous bytes -> one full cache line.
    const __hip_bfloat16* pA = Ebf + (size_t)(tileI + wr * 64 + l16) * DIM + quad * 8;
    const __hip_bfloat16* pB = Ebf + (size_t)(tileJ + wc * 64 + l16) * DIM + quad * 8;

    f32x4 acc[4][4] = {};
    bf16x8 a[2][4], b[2][4];

    #pragma unroll
    for (int i = 0; i < 4; i++) {
        a[0][i] = *(const bf16x8*)(pA + i * 16 * DIM);
        b[0][i] = *(const bf16x8*)(pB + i * 16 * DIM);
    }
    #pragma unroll
    for (int kk = 0; kk < 16; ++kk) {      // 16 K-steps of 32
        const int cur = kk & 1, nxt = cur ^ 1;   // compile-time after unroll
        if (kk < 15) {
            #pragma unroll
            for (int i = 0; i < 4; i++) {
                a[nxt][i] = *(const bf16x8*)(pA + i * 16 * DIM + (kk + 1) * 32);
                b[nxt][i] = *(const bf16x8*)(pB + i * 16 * DIM + (kk + 1) * 32);
            }
        }
        #pragma unroll
        for (int mi = 0; mi < 4; mi++)
            #pragma unroll
            for (int ni = 0; ni < 4; ni++)
                acc[mi][ni] = __builtin_amdgcn_mfma_f32_16x16x32_bf16(
                    a[cur][mi], b[cur][ni], acc[mi][ni], 0, 0, 0);
    }

    // C/D layout: col = wc*64+ni*16+l16 (lane), row = wr*64+mi*16+quad*4+reg
    int rl[16], cl[4], clocv[4];
    #pragma unroll
    for (int mi = 0; mi < 4; mi++)
        #pragma unroll
        for (int reg = 0; reg < 4; reg++)
            rl[mi * 4 + reg] = rowLab[wr * 64 + mi * 16 + quad * 4 + reg];
    #pragma unroll
    for (int ni = 0; ni < 4; ni++) {
        clocv[ni] = wc * 64 + ni * 16 + l16;
        cl[ni] = colLab[clocv[ni]];
    }

    // ---- row pass: reduce over this tile's columns, for rows of tileI ----
    #pragma unroll
    for (int mi = 0; mi < 4; mi++) {
        #pragma unroll
        for (int reg = 0; reg < 4; reg++) {
            const int rloc = wr * 64 + mi * 16 + quad * 4 + reg;
            const int lr   = rl[mi * 4 + reg];
            const int gi   = tileI + rloc;
            float pmin =  INFINITY;
            float nmax = -INFINITY;
            #pragma unroll
            for (int ni = 0; ni < 4; ni++) {
                const int gj  = tileJ + clocv[ni];
                const float g = acc[mi][ni][reg];
                const bool same = (lr == cl[ni]);
                if (same && gi != gj) pmin = fminf(pmin, g);
                if (!same)            nmax = fmaxf(nmax, g);
            }
            #pragma unroll
            for (int m = 1; m < 16; m <<= 1) {
                pmin = fminf(pmin, __shfl_xor(pmin, m));
                nmax = fmaxf(nmax, __shfl_xor(nmax, m));
            }
            if (l16 == 0) {
                if (pmin <  INFINITY) atomicMin(&posArr[gi], enc(pmin));
                if (nmax > -INFINITY) atomicMax(&negArr[gi], enc(nmax));
            }
        }
    }

    // ---- col pass (off-diag only): reduce over rows, for rows of tileJ ----
    if (!diag) {
        #pragma unroll
        for (int ni = 0; ni < 4; ni++) {
            const int lc = cl[ni];
            const int gj = tileJ + clocv[ni];
            float pmin =  INFINITY;
            float nmax = -INFINITY;
            #pragma unroll
            for (int mi = 0; mi < 4; mi++) {
                #pragma unroll
                for (int reg = 0; reg < 4; reg++) {
                    const float g = acc[mi][ni][reg];
                    const bool same = (rl[mi * 4 + reg] == lc);
                    if (same) pmin = fminf(pmin, g);
                    else      nmax = fmaxf(nmax, g);
                }
            }
            pmin = fminf(pmin, __shfl_xor(pmin, 16));
            pmin = fminf(pmin, __shfl_xor(pmin, 32));
            nmax = fmaxf(nmax, __shfl_xor(nmax, 16));
            nmax = fmaxf(nmax, __shfl_xor(nmax, 32));
            if (quad == 0) {
                if (pmin <  INFINITY) atomicMin(&posArr[gj], enc(pmin));
                if (nmax > -INFINITY) atomicMax(&negArr[gj], enc(nmax));
            }
        }
    }
}

// ---- kernel 3: per-row loss + mean over valid rows ----
__global__ void tl_final(const unsigned* __restrict__ posArr,
                         const unsigned* __restrict__ negArr,
                         float* __restrict__ out) {
    const int tid = threadIdx.x; // 1024 threads, 4 rows each, single pass
    uint4 pe4 = ((const uint4*)posArr)[tid];
    uint4 ne4 = ((const uint4*)negArr)[tid];
    unsigned pes[4] = {pe4.x, pe4.y, pe4.z, pe4.w};
    unsigned nes[4] = {ne4.x, ne4.y, ne4.z, ne4.w};
    float sum = 0.0f;
    int   count = 0;
    #pragma unroll
    for (int j = 0; j < 4; j++) {
        const bool valid = (pes[j] != POS_INIT) && (nes[j] != NEG_INIT);
        const float dap = sqrtf(fmaxf(2.0f - 2.0f * dec(pes[j]), 0.0f));
        const float dan = sqrtf(fmaxf(2.0f - 2.0f * dec(nes[j]), 0.0f));
        const float per = fmaxf(dap - dan + MARGIN, 0.0f);
        if (valid) { sum += per; count += 1; }
    }
    #pragma unroll
    for (int m = 32; m >= 1; m >>= 1) {
        sum   += __shfl_xor(sum, m);
        count += __shfl_xor(count, m);
    }
    __shared__ float ssum[16];
    __shared__ int   scnt[16];
    const int wave = tid >> 6, lane = tid & 63;
    if (lane == 0) { ssum[wave] = sum; scnt[wave] = count; }
    __syncthreads();
    if (tid == 0) {
        float s = 0.0f; int c = 0;
        #pragma unroll
        for (int w = 0; w < 16; w++) { s += ssum[w]; c += scnt[w]; }
        out[0] = (c > 0) ? (s / (float)c) : 0.0f;
    }
}

extern "C" void kernel_launch(void* const* d_in, const int* in_sizes, int n_in,
                              void* d_out, int out_size, void* d_ws, size_t ws_size,
                              hipStream_t stream) {
    const float* E      = (const float*)d_in[0];
    const int*   labels = (const int*)d_in[1];
    float*       out    = (float*)d_out;

    char* ws = (char*)d_ws;
    __hip_bfloat16* Ebf   = (__hip_bfloat16*)ws;                       // 4 MB
    unsigned* posArr      = (unsigned*)(ws + (size_t)NROW * DIM * 2);  // 16 KB
    unsigned* negArr      = posArr + NROW;                             // 16 KB

    tl_norm<<<NROW / 4, 256, 0, stream>>>(E, Ebf, posArr, negArr);
    tl_gram<<<NPAIR, 256, 0, stream>>>(Ebf, labels, posArr, negArr);
    tl_final<<<1, 1024, 0, stream>>>(posArr, negArr, out);
}

// Round 2
// 89.182 us; speedup vs baseline: 1.3041x; 1.3041x over previous
//
#include <hip/hip_runtime.h>
#include <hip/hip_bf16.h>
#include <stdint.h>

// BatchHardTripletLoss: N=4096, D=512, C=128, margin=0.3
// dist monotone-decreasing in gram => hardest-pos = min gram (same label, j!=i),
// hardest-neg = max gram (diff label). Gram symmetric => upper-triangular tiles.
//
// R2: R1's direct-from-L2 fragment loads were 16-line-at-1KB-stride per wave
// instruction (latency/request bound: MfmaUtil 5.6%, all pipes idle). Fix: store
// Ebf in an MFMA-native swizzled layout so each fragment load is ONE contiguous
// 1KB wave transaction:
//   16B-unit offset(row, kchunk) = ktile*16384 + rtile*64 + c_in*16 + r_in
//   where kchunk=k/8, ktile=kchunk/4, c_in=kchunk&3, rtile=row/16, r_in=row&15.
// Fragment (rowbase, kk): lane offset = quad*16+l16 = lane -> contiguous.
// Also: prefetch ring depth 4 (compile-time indices), bijective XCD swizzle
// (528%8==0), zero barriers in the K-loop. Epilogue identical to verified kernel.

#define NROW 4096
#define DIM  512
#define MARGIN 0.3f
#define BT 128
#define NTILE (NROW / BT)                 // 32
#define NPAIR (NTILE * (NTILE + 1) / 2)   // 528
#define POS_INIT 0xFFFFFFFFu
#define NEG_INIT 0u

typedef __attribute__((ext_vector_type(8))) __bf16 bf16x8;
typedef __attribute__((ext_vector_type(4))) float  f32x4;
typedef __attribute__((ext_vector_type(8))) unsigned short u16x8;

// monotone float<->uint: order-preserving for atomicMin/Max on unsigned.
// enc(finite f) can never equal POS_INIT (needs NaN) nor NEG_INIT (needs -NaN),
// so the init sentinels double as "no positive/negative seen" flags.
__device__ __forceinline__ unsigned enc(float f) {
    unsigned u = __float_as_uint(f);
    return (u & 0x80000000u) ? ~u : (u | 0x80000000u);
}
__device__ __forceinline__ float dec(unsigned e) {
    return (e & 0x80000000u) ? __uint_as_float(e & 0x7fffffffu)
                             : __uint_as_float(~e);
}

__device__ __forceinline__ unsigned short f2bf(float f) {
    __hip_bfloat16 h = __float2bfloat16(f);
    return *reinterpret_cast<unsigned short*>(&h);
}

// ---- kernel 1: L2-normalize rows -> bf16 in swizzled layout, + init arrays ----
// one wave per row; 4 waves/block; 1024 blocks (first 16 also init pos/neg)
__global__ void tl_norm(const float* __restrict__ E,
                        __hip_bfloat16* __restrict__ Ebf,
                        unsigned* __restrict__ posArr,
                        unsigned* __restrict__ negArr) {
    if (blockIdx.x < 16) {
        int t = blockIdx.x * 256 + threadIdx.x;   // covers 4096
        posArr[t] = POS_INIT;
        negArr[t] = NEG_INIT;
    }
    int wave = threadIdx.x >> 6;
    int lane = threadIdx.x & 63;
    int row  = blockIdx.x * 4 + wave;

    // lane l owns kchunk l = 8 consecutive floats (bytes 32l..32l+31).
    const float4* src = (const float4*)(E + (size_t)row * DIM);
    float4 v0 = src[2 * lane];
    float4 v1 = src[2 * lane + 1];
    float ss = v0.x*v0.x + v0.y*v0.y + v0.z*v0.z + v0.w*v0.w
             + v1.x*v1.x + v1.y*v1.y + v1.z*v1.z + v1.w*v1.w;
    #pragma unroll
    for (int m = 32; m >= 1; m >>= 1) ss += __shfl_xor(ss, m);
    float inv = 1.0f / fmaxf(sqrtf(ss), 1e-12f);

    u16x8 o;
    o[0] = f2bf(v0.x * inv); o[1] = f2bf(v0.y * inv);
    o[2] = f2bf(v0.z * inv); o[3] = f2bf(v0.w * inv);
    o[4] = f2bf(v1.x * inv); o[5] = f2bf(v1.y * inv);
    o[6] = f2bf(v1.z * inv); o[7] = f2bf(v1.w * inv);

    // swizzled store: lane l is kchunk l of this row
    const int ktile = lane >> 2, c_in = lane & 3;
    const int rtile = row >> 4,  r_in = row & 15;
    const size_t off16 = (size_t)ktile * 16384 + (size_t)rtile * 64
                       + (size_t)c_in * 16 + r_in;       // in 16B units
    ((u16x8*)Ebf)[off16] = o;
}

// ---- kernel 2: upper-triangular bf16 MFMA Gram, swizzled direct-L2 frags ----
// 128x128 tile per block, 4 waves in 2x2, each wave 4x4 of 16x16x32 MFMA.
// No LDS staging, no barriers in the K-loop: 4-deep register prefetch ring.
__global__ void __launch_bounds__(256, 2)
tl_gram(const __hip_bfloat16* __restrict__ Ebf,
        const int* __restrict__ labels,
        unsigned* __restrict__ posArr,
        unsigned* __restrict__ negArr) {
    __shared__ int rowLab[BT];
    __shared__ int colLab[BT];

    // bijective XCD swizzle: 528 blocks, 8 XCDs, 66 consecutive logical
    // blocks per XCD -> consecutive bi (shared A panel) co-resident in one L2.
    int bid = blockIdx.x;
    int t = (bid & 7) * (NPAIR / 8) + (bid >> 3);

    // triangular decode: t -> (bi, bj) with bi <= bj
    int bi = 0, rowlen = NTILE;
    while (t >= rowlen) { t -= rowlen; rowlen--; bi++; }
    const int bj = bi + t;

    const int tid  = threadIdx.x;
    const int wave = tid >> 6;
    const int lane = tid & 63;
    const int quad = lane >> 4;
    const int l16  = lane & 15;
    const int wr   = wave >> 1;   // wave row (0..1): rows wr*64..+63
    const int wc   = wave & 1;    // wave col (0..1): cols wc*64..+63
    const int tileI = bi * BT;
    const int tileJ = bj * BT;
    const bool diag = (bi == bj);

    if (tid < BT) rowLab[tid] = labels[tileI + tid];
    else          colLab[tid - BT] = labels[tileJ + (tid - BT)];
    __syncthreads();   // the only block-wide sync

    // swizzled layout: frag(rowbase, kk) at 16B-unit offset
    //   kk*16384 + (rowbase/16)*64 + lane      (fully lane-contiguous 1KB)
    const bf16x8* Ev = (const bf16x8*)Ebf;
    const bf16x8* Ea = Ev + ((tileI + wr * 64) >> 4) * 64 + lane;
    const bf16x8* Eb = Ev + ((tileJ + wc * 64) >> 4) * 64 + lane;

    f32x4 acc[4][4] = {};
    bf16x8 a[4][4], b[4][4];   // [ring slot][frag] — all indices compile-time

    #pragma unroll
    for (int p = 0; p < 3; ++p) {
        #pragma unroll
        for (int i = 0; i < 4; i++) {
            a[p][i] = Ea[p * 16384 + i * 64];
            b[p][i] = Eb[p * 16384 + i * 64];
        }
    }
    #pragma unroll
    for (int kk = 0; kk < 16; ++kk) {      // 16 K-steps of 32
        const int cur = kk & 3;
        if (kk + 3 < 16) {
            const int nxt = (kk + 3) & 3;
            #pragma unroll
            for (int i = 0; i < 4; i++) {
                a[nxt][i] = Ea[(kk + 3) * 16384 + i * 64];
                b[nxt][i] = Eb[(kk + 3) * 16384 + i * 64];
            }
        }
        #pragma unroll
        for (int mi = 0; mi < 4; mi++)
            #pragma unroll
            for (int ni = 0; ni < 4; ni++)
                acc[mi][ni] = __builtin_amdgcn_mfma_f32_16x16x32_bf16(
                    a[cur][mi], b[cur][ni], acc[mi][ni], 0, 0, 0);
    }

    // C/D layout: col = wc*64+ni*16+l16 (lane), row = wr*64+mi*16+quad*4+reg
    int rl[16], cl[4], clocv[4];
    #pragma unroll
    for (int mi = 0; mi < 4; mi++)
        #pragma unroll
        for (int reg = 0; reg < 4; reg++)
            rl[mi * 4 + reg] = rowLab[wr * 64 + mi * 16 + quad * 4 + reg];
    #pragma unroll
    for (int ni = 0; ni < 4; ni++) {
        clocv[ni] = wc * 64 + ni * 16 + l16;
        cl[ni] = colLab[clocv[ni]];
    }

    // ---- row pass: reduce over this tile's columns, for rows of tileI ----
    #pragma unroll
    for (int mi = 0; mi < 4; mi++) {
        #pragma unroll
        for (int reg = 0; reg < 4; reg++) {
            const int rloc = wr * 64 + mi * 16 + quad * 4 + reg;
            const int lr   = rl[mi * 4 + reg];
            const int gi   = tileI + rloc;
            float pmin =  INFINITY;
            float nmax = -INFINITY;
            #pragma unroll
            for (int ni = 0; ni < 4; ni++) {
                const int gj  = tileJ + clocv[ni];
                const float g = acc[mi][ni][reg];
                const bool same = (lr == cl[ni]);
                if (same && gi != gj) pmin = fminf(pmin, g);
                if (!same)            nmax = fmaxf(nmax, g);
            }
            #pragma unroll
            for (int m = 1; m < 16; m <<= 1) {
                pmin = fminf(pmin, __shfl_xor(pmin, m));
                nmax = fmaxf(nmax, __shfl_xor(nmax, m));
            }
            if (l16 == 0) {
                if (pmin <  INFINITY) atomicMin(&posArr[gi], enc(pmin));
                if (nmax > -INFINITY) atomicMax(&negArr[gi], enc(nmax));
            }
        }
    }

    // ---- col pass (off-diag only): reduce over rows, for rows of tileJ ----
    if (!diag) {
        #pragma unroll
        for (int ni = 0; ni < 4; ni++) {
            const int lc = cl[ni];
            const int gj = tileJ + clocv[ni];
            float pmin =  INFINITY;
            float nmax = -INFINITY;
            #pragma unroll
            for (int mi = 0; mi < 4; mi++) {
                #pragma unroll
                for (int reg = 0; reg < 4; reg++) {
                    const float g = acc[mi][ni][reg];
                    const bool same = (rl[mi * 4 + reg] == lc);
                    if (same) pmin = fminf(pmin, g);
                    else      nmax = fmaxf(nmax, g);
                }
            }
            pmin = fminf(pmin, __shfl_xor(pmin, 16));
            pmin = fminf(pmin, __shfl_xor(pmin, 32));
            nmax = fmaxf(nmax, __shfl_xor(nmax, 16));
            nmax = fmaxf(nmax, __shfl_xor(nmax, 32));
            if (quad == 0) {
                if (pmin <  INFINITY) atomicMin(&posArr[gj], enc(pmin));
                if (nmax > -INFINITY) atomicMax(&negArr[gj], enc(nmax));
            }
        }
    }
}

// ---- kernel 3: per-row loss + mean over valid rows ----
__global__ void tl_final(const unsigned* __restrict__ posArr,
                         const unsigned* __restrict__ negArr,
                         float* __restrict__ out) {
    const int tid = threadIdx.x; // 1024 threads, 4 rows each, single pass
    uint4 pe4 = ((const uint4*)posArr)[tid];
    uint4 ne4 = ((const uint4*)negArr)[tid];
    unsigned pes[4] = {pe4.x, pe4.y, pe4.z, pe4.w};
    unsigned nes[4] = {ne4.x, ne4.y, ne4.z, ne4.w};
    float sum = 0.0f;
    int   count = 0;
    #pragma unroll
    for (int j = 0; j < 4; j++) {
        const bool valid = (pes[j] != POS_INIT) && (nes[j] != NEG_INIT);
        const float dap = sqrtf(fmaxf(2.0f - 2.0f * dec(pes[j]), 0.0f));
        const float dan = sqrtf(fmaxf(2.0f - 2.0f * dec(nes[j]), 0.0f));
        const float per = fmaxf(dap - dan + MARGIN, 0.0f);
        if (valid) { sum += per; count += 1; }
    }
    #pragma unroll
    for (int m = 32; m >= 1; m >>= 1) {
        sum   += __shfl_xor(sum, m);
        count += __shfl_xor(count, m);
    }
    __shared__ float ssum[16];
    __shared__ int   scnt[16];
    const int wave = tid >> 6, lane = tid & 63;
    if (lane == 0) { ssum[wave] = sum; scnt[wave] = count; }
    __syncthreads();
    if (tid == 0) {
        float s = 0.0f; int c = 0;
        #pragma unroll
        for (int w = 0; w < 16; w++) { s += ssum[w]; c += scnt[w]; }
        out[0] = (c > 0) ? (s / (float)c) : 0.0f;
    }
}

extern "C" void kernel_launch(void* const* d_in, const int* in_sizes, int n_in,
                              void* d_out, int out_size, void* d_ws, size_t ws_size,
                              hipStream_t stream) {
    const float* E      = (const float*)d_in[0];
    const int*   labels = (const int*)d_in[1];
    float*       out    = (float*)d_out;

    char* ws = (char*)d_ws;
    __hip_bfloat16* Ebf   = (__hip_bfloat16*)ws;                       // 4 MB
    unsigned* posArr      = (unsigned*)(ws + (size_t)NROW * DIM * 2);  // 16 KB
    unsigned* negArr      = posArr + NROW;                             // 16 KB

    tl_norm<<<NROW / 4, 256, 0, stream>>>(E, Ebf, posArr, negArr);
    tl_gram<<<NPAIR, 256, 0, stream>>>(Ebf, labels, posArr, negArr);
    tl_final<<<1, 1024, 0, stream>>>(posArr, negArr, out);
}